// Round 3
// baseline (292.739 us; speedup 1.0000x reference)
//
#include <hip/hip_runtime.h>

// BoundaryChunker — MI355X (gfx950), round 3
// Pipeline: pack(+dtype detect, zero-fill) -> wconv -> pool -> MFMA GEMM.
// Round-3 change: GEMM is register-double-buffered (ping-pong fragment sets,
// prefetch distance 1, full K unroll) to fix the latency-bound 5.6% MfmaUtil
// seen in round 2; + s_setprio around MFMA; + bijective XCD swizzle (bn-major)
// for W-panel L2 locality.

#define B_ 8
#define L_ 4096
#define D_ 1024
#define POOLW 5
#define EPS_ 1e-6f

typedef __attribute__((ext_vector_type(8))) short bf16x8;
typedef __attribute__((ext_vector_type(4))) float f32x4;

__device__ __forceinline__ unsigned short bf16_rne(float v) {
    unsigned u = __float_as_uint(v);
    unsigned r = u + 0x7FFFu + ((u >> 16) & 1u);
    return (unsigned short)(r >> 16);
}
__device__ __forceinline__ float bf16_f32(unsigned short h) {
    return __uint_as_float(((unsigned)h) << 16);
}

__device__ __forceinline__ int mask_val(const void* mask, int flag, int i) {
    if (flag == 0) return ((const unsigned char*)mask)[i] != 0;
    if (flag == 1) return ((const int*)mask)[i] != 0;
    return ((const float*)mask)[i] != 0.0f;
}

// ------------------------------------------------------------------ pack ----
__global__ __launch_bounds__(256) void pack_kernel(
    const void* __restrict__ mask, const float* __restrict__ conf_in,
    int* __restrict__ counts, int* __restrict__ t_idx,
    float* __restrict__ out_mask, float* __restrict__ out_idx,
    float* __restrict__ out_conf, int U) {
    const int b   = blockIdx.x;
    const int tid = threadIdx.x;
    __shared__ int s_clo, s_chi, s_flag;
    __shared__ int scan[256];
    if (tid == 0) { s_clo = 0; s_chi = 0; }
    __syncthreads();
    // dtype detect on this block's 4KB slice of raw bytes:
    // i32(1) -> only byte%4==0 nonzero; f32(1.0f) -> only high bytes; u8 -> both.
    const uint4 wv = ((const uint4*)mask)[b * 256 + tid];
    const unsigned wd[4] = {wv.x, wv.y, wv.z, wv.w};
    int clo = 0, chi = 0;
#pragma unroll
    for (int i = 0; i < 4; ++i) {
        clo += ((wd[i] & 0x000000FFu) != 0u);
        chi += ((wd[i] & 0xFFFFFF00u) != 0u);
    }
    if (clo) atomicAdd(&s_clo, clo);
    if (chi) atomicAdd(&s_chi, chi);
    // zero-fill packed small outputs (d_out is re-poisoned before every call)
    for (int u = tid; u < U; u += 256) {
        out_mask[b * U + u] = 0.0f;
        out_idx[b * U + u]  = 0.0f;
        out_conf[b * U + u] = 0.0f;
    }
    __syncthreads();
    if (tid == 0) s_flag = (s_chi == 0) ? 1 : ((s_clo == 0) ? 2 : 0);
    __syncthreads();
    const int flag = s_flag;
    const int base = b * L_;
    int vals[16];
    int cnt = 0;
#pragma unroll
    for (int j = 0; j < 16; ++j) {
        int v = mask_val(mask, flag, base + tid * 16 + j);
        vals[j] = v;
        cnt += v;
    }
    scan[tid] = cnt;
    __syncthreads();
    for (int off = 1; off < 256; off <<= 1) {
        int v   = scan[tid];
        int add = (tid >= off) ? scan[tid - off] : 0;
        __syncthreads();
        scan[tid] = v + add;
        __syncthreads();
    }
    const int excl = scan[tid] - cnt;
    if (tid == 0) counts[b] = scan[255];
    int u = excl;
#pragma unroll
    for (int j = 0; j < 16; ++j) {
        if (vals[j]) {
            const int t = tid * 16 + j;
            t_idx[b * U + u]    = t;
            out_mask[b * U + u] = 1.0f;
            out_idx[b * U + u]  = (float)t;
            out_conf[b * U + u] = conf_in[base + t];
            ++u;
        }
    }
}

// ----------------------------------------------------------------- wconv ----
__global__ __launch_bounds__(256) void wconv_kernel(
    const float* __restrict__ W, unsigned short* __restrict__ Whi,
    unsigned short* __restrict__ Wlo) {
    const int i = (blockIdx.x * 256 + threadIdx.x) * 4;
    const float4 v = *(const float4*)&W[i];
    ushort4 hi, lo;
    hi.x = bf16_rne(v.x); lo.x = bf16_rne(v.x - bf16_f32(hi.x));
    hi.y = bf16_rne(v.y); lo.y = bf16_rne(v.y - bf16_f32(hi.y));
    hi.z = bf16_rne(v.z); lo.z = bf16_rne(v.z - bf16_f32(hi.z));
    hi.w = bf16_rne(v.w); lo.w = bf16_rne(v.w - bf16_f32(hi.w));
    *(ushort4*)&Whi[i] = hi;
    *(ushort4*)&Wlo[i] = lo;
}

// ------------------------------------------------------------------ pool ----
__global__ __launch_bounds__(256) void pool_kernel(
    const float* __restrict__ emb, const float* __restrict__ cs,
    const int* __restrict__ counts, const int* __restrict__ t_idx,
    unsigned short* __restrict__ Phi, unsigned short* __restrict__ Plo,
    int U) {
    const int m = blockIdx.x;  // b*U + u
    const int b = m / U, u = m - b * U;
    if (u >= counts[b]) return;
    const int t     = t_idx[m];
    const int start = (t - POOLW + 1) > 0 ? (t - POOLW + 1) : 0;
    float wsum = 0.f;
    for (int s = start; s <= t; ++s) wsum += cs[b * L_ + s];
    const float inv = 1.0f / (wsum + EPS_);
    const int d0 = threadIdx.x * 4;
    float4 acc = make_float4(0.f, 0.f, 0.f, 0.f);
    for (int s = start; s <= t; ++s) {
        const float w  = cs[b * L_ + s];
        const float4 e = *(const float4*)&emb[((size_t)(b * L_ + s)) * D_ + d0];
        acc.x += w * e.x; acc.y += w * e.y; acc.z += w * e.z; acc.w += w * e.w;
    }
    acc.x *= inv; acc.y *= inv; acc.z *= inv; acc.w *= inv;
    ushort4 hi, lo;
    hi.x = bf16_rne(acc.x); lo.x = bf16_rne(acc.x - bf16_f32(hi.x));
    hi.y = bf16_rne(acc.y); lo.y = bf16_rne(acc.y - bf16_f32(hi.y));
    hi.z = bf16_rne(acc.z); lo.z = bf16_rne(acc.z - bf16_f32(hi.z));
    hi.w = bf16_rne(acc.w); lo.w = bf16_rne(acc.w - bf16_f32(hi.w));
    *(ushort4*)&Phi[(size_t)m * D_ + d0] = hi;
    *(ushort4*)&Plo[(size_t)m * D_ + d0] = lo;
}

// ------------------------------------------------------------------ gemm ----
// C[m,n] = sum_k P[m,k]*W[n,k] + bias[n] via mfma_f32_16x16x32_bf16,
// split-bf16 (AhBh + AhBl + AlBh). Block 64x64 / 4 waves 2x2 / wave 32x32.
// Register double-buffer: two named FragSets, prefetch distance 1.
struct FragSet {
    bf16x8 ah0, ah1, al0, al1, bh0, bh1, bl0, bl1;
};

__device__ __forceinline__ void load_set(
    FragSet& s, const unsigned short* __restrict__ Phi,
    const unsigned short* __restrict__ Plo,
    const unsigned short* __restrict__ Whi,
    const unsigned short* __restrict__ Wlo, size_t aoff0, size_t aoff1,
    size_t boff0, size_t boff1, int k) {
    s.ah0 = *(const bf16x8*)(Phi + aoff0 + k);
    s.ah1 = *(const bf16x8*)(Phi + aoff1 + k);
    s.al0 = *(const bf16x8*)(Plo + aoff0 + k);
    s.al1 = *(const bf16x8*)(Plo + aoff1 + k);
    s.bh0 = *(const bf16x8*)(Whi + boff0 + k);
    s.bh1 = *(const bf16x8*)(Whi + boff1 + k);
    s.bl0 = *(const bf16x8*)(Wlo + boff0 + k);
    s.bl1 = *(const bf16x8*)(Wlo + boff1 + k);
}

__device__ __forceinline__ void mfma_set(const FragSet& s, f32x4 acc[2][2]) {
    __builtin_amdgcn_s_setprio(1);
    acc[0][0] = __builtin_amdgcn_mfma_f32_16x16x32_bf16(s.ah0, s.bh0, acc[0][0], 0, 0, 0);
    acc[0][1] = __builtin_amdgcn_mfma_f32_16x16x32_bf16(s.ah0, s.bh1, acc[0][1], 0, 0, 0);
    acc[1][0] = __builtin_amdgcn_mfma_f32_16x16x32_bf16(s.ah1, s.bh0, acc[1][0], 0, 0, 0);
    acc[1][1] = __builtin_amdgcn_mfma_f32_16x16x32_bf16(s.ah1, s.bh1, acc[1][1], 0, 0, 0);
    acc[0][0] = __builtin_amdgcn_mfma_f32_16x16x32_bf16(s.ah0, s.bl0, acc[0][0], 0, 0, 0);
    acc[0][1] = __builtin_amdgcn_mfma_f32_16x16x32_bf16(s.ah0, s.bl1, acc[0][1], 0, 0, 0);
    acc[1][0] = __builtin_amdgcn_mfma_f32_16x16x32_bf16(s.ah1, s.bl0, acc[1][0], 0, 0, 0);
    acc[1][1] = __builtin_amdgcn_mfma_f32_16x16x32_bf16(s.ah1, s.bl1, acc[1][1], 0, 0, 0);
    acc[0][0] = __builtin_amdgcn_mfma_f32_16x16x32_bf16(s.al0, s.bh0, acc[0][0], 0, 0, 0);
    acc[0][1] = __builtin_amdgcn_mfma_f32_16x16x32_bf16(s.al0, s.bh1, acc[0][1], 0, 0, 0);
    acc[1][0] = __builtin_amdgcn_mfma_f32_16x16x32_bf16(s.al1, s.bh0, acc[1][0], 0, 0, 0);
    acc[1][1] = __builtin_amdgcn_mfma_f32_16x16x32_bf16(s.al1, s.bh1, acc[1][1], 0, 0, 0);
    __builtin_amdgcn_s_setprio(0);
}

__global__ __launch_bounds__(256) void gemm_kernel(
    const unsigned short* __restrict__ Phi, const unsigned short* __restrict__ Plo,
    const unsigned short* __restrict__ Whi, const unsigned short* __restrict__ Wlo,
    const float* __restrict__ bias, const int* __restrict__ counts,
    float* __restrict__ C, int M, int U, int MB, int NB) {
    // bijective XCD swizzle (m204): 8 contiguous grid chunks, one per XCD.
    const int nb  = MB * NB;
    const int q   = nb >> 3, r = nb & 7;
    const int xcd = blockIdx.x & 7, pos = blockIdx.x >> 3;
    const int wg  = (xcd < r ? xcd * (q + 1) : r * (q + 1) + (xcd - r) * q) + pos;
    const int bxm = wg % MB;       // bn-major: consecutive wg share the W panel
    const int byn = wg / MB;

    const int tid  = threadIdx.x;
    const int w    = tid >> 6;
    const int lane = tid & 63;
    const int bm = bxm * 64, bn = byn * 64;
    const int wm = (w >> 1) * 32, wn = (w & 1) * 32;
    const int lr = lane & 15;
    const int lk = (lane >> 4) * 8;

    const size_t aoff0 = (size_t)(bm + wm + lr) * D_ + lk;
    const size_t aoff1 = aoff0 + (size_t)16 * D_;
    const size_t boff0 = (size_t)(bn + wn + lr) * D_ + lk;
    const size_t boff1 = boff0 + (size_t)16 * D_;

    f32x4 acc[2][2] = {};
    FragSet s0, s1;
    load_set(s0, Phi, Plo, Whi, Wlo, aoff0, aoff1, boff0, boff1, 0);
#pragma unroll
    for (int k = 0; k < D_; k += 64) {
        load_set(s1, Phi, Plo, Whi, Wlo, aoff0, aoff1, boff0, boff1, k + 32);
        mfma_set(s0, acc);
        if (k + 64 < D_)
            load_set(s0, Phi, Plo, Whi, Wlo, aoff0, aoff1, boff0, boff1, k + 64);
        mfma_set(s1, acc);
    }
    // epilogue: bias + zero inactive slots
#pragma unroll
    for (int i = 0; i < 2; ++i)
#pragma unroll
        for (int j = 0; j < 2; ++j) {
            const int n  = bn + wn + j * 16 + lr;
            const float bv = bias[n];
#pragma unroll
            for (int rr = 0; rr < 4; ++rr) {
                const int m = bm + wm + i * 16 + (lane >> 4) * 4 + rr;
                if (m >= M) continue;
                const int b_ = m / U;
                const int u  = m - b_ * U;
                const float val =
                    (u < counts[b_]) ? (acc[i][j][rr] + bv) : 0.0f;
                C[(size_t)m * D_ + n] = val;
            }
        }
}

// ---------------------------------------------------------------- launch ----
extern "C" void kernel_launch(void* const* d_in, const int* in_sizes, int n_in,
                              void* d_out, int out_size, void* d_ws,
                              size_t ws_size, hipStream_t stream) {
    const float* emb     = (const float*)d_in[0];
    const void*  mask    = d_in[1];
    const float* cs      = (const float*)d_in[2];
    const float* conf_in = (const float*)d_in[3];
    const float* W       = (const float*)d_in[4];
    const float* bias    = (const float*)d_in[5];

    const int U    = out_size / (B_ * (D_ + 3));
    const int M    = B_ * U;
    const int Mpad = (M + 63) & ~63;

    float* out_chunks = (float*)d_out;                  // (B,U,D)
    float* out_mask   = out_chunks + (size_t)M * D_;    // (B,U)
    float* out_idx    = out_mask + M;                   // (B,U)
    float* out_conf   = out_idx + M;                    // (B,U)

    // workspace layout (16B-aligned chunks)
    char* ws = (char*)d_ws;
    int* counts = (int*)ws;                                   // 8 ints
    int* t_idx  = (int*)(ws + 256);                           // Mpad ints
    size_t off  = (256 + (size_t)Mpad * 4 + 255) & ~(size_t)255;
    unsigned short* Phi = (unsigned short*)(ws + off);        // Mpad*D bf16
    off += (size_t)Mpad * D_ * 2;
    unsigned short* Plo = (unsigned short*)(ws + off);
    off += (size_t)Mpad * D_ * 2;
    unsigned short* Whi = (unsigned short*)(ws + off);        // D*D bf16
    off += (size_t)D_ * D_ * 2;
    unsigned short* Wlo = (unsigned short*)(ws + off);

    pack_kernel<<<B_, 256, 0, stream>>>(mask, conf_in, counts, t_idx,
                                        out_mask, out_idx, out_conf, U);
    wconv_kernel<<<D_ * D_ / 1024, 256, 0, stream>>>(W, Whi, Wlo);
    pool_kernel<<<M, 256, 0, stream>>>(emb, cs, counts, t_idx, Phi, Plo, U);
    const int MB = Mpad / 64, NB = D_ / 64;
    gemm_kernel<<<MB * NB, 256, 0, stream>>>(Phi, Plo, Whi, Wlo, bias, counts,
                                             out_chunks, M, U, MB, NB);
}

// Round 4
// 283.981 us; speedup vs baseline: 1.0308x; 1.0308x over previous
//
#include <hip/hip_runtime.h>

// BoundaryChunker — MI355X (gfx950), round 4
// Pipeline: memset(chunks) -> pack(+dtype detect) -> wconv -> pool -> GEMM.
// Round-4 change: split-K GEMM (KSPLIT=4, atomicAdd partials). Round 3 showed
// the GEMM is latency-bound with only 9 waves/CU (grid-bound occupancy);
// split-K quadruples resident waves -> 4x MLP. XCD swizzle switched to
// m-chunked so each XCD's A-slice (1.2MB) stays L2-resident; W is L3-shared.

#define B_ 8
#define L_ 4096
#define D_ 1024
#define POOLW 5
#define EPS_ 1e-6f
#define KSPLIT 4
#define KCHUNK (D_ / KSPLIT)   // 256
#define NB_ 16                 // D_/64 n-tiles

typedef __attribute__((ext_vector_type(8))) short bf16x8;
typedef __attribute__((ext_vector_type(4))) float f32x4;

__device__ __forceinline__ unsigned short bf16_rne(float v) {
    unsigned u = __float_as_uint(v);
    unsigned r = u + 0x7FFFu + ((u >> 16) & 1u);
    return (unsigned short)(r >> 16);
}
__device__ __forceinline__ float bf16_f32(unsigned short h) {
    return __uint_as_float(((unsigned)h) << 16);
}

__device__ __forceinline__ int mask_val(const void* mask, int flag, int i) {
    if (flag == 0) return ((const unsigned char*)mask)[i] != 0;
    if (flag == 1) return ((const int*)mask)[i] != 0;
    return ((const float*)mask)[i] != 0.0f;
}

// ------------------------------------------------------------------ pack ----
__global__ __launch_bounds__(256) void pack_kernel(
    const void* __restrict__ mask, const float* __restrict__ conf_in,
    int* __restrict__ counts, int* __restrict__ t_idx,
    float* __restrict__ out_mask, float* __restrict__ out_idx,
    float* __restrict__ out_conf, int U) {
    const int b   = blockIdx.x;
    const int tid = threadIdx.x;
    __shared__ int s_clo, s_chi, s_flag;
    __shared__ int scan[256];
    if (tid == 0) { s_clo = 0; s_chi = 0; }
    __syncthreads();
    // dtype detect on this block's 4KB slice of raw bytes:
    // i32(1) -> only byte%4==0 nonzero; f32(1.0f) -> only high bytes; u8 -> both.
    const uint4 wv = ((const uint4*)mask)[b * 256 + tid];
    const unsigned wd[4] = {wv.x, wv.y, wv.z, wv.w};
    int clo = 0, chi = 0;
#pragma unroll
    for (int i = 0; i < 4; ++i) {
        clo += ((wd[i] & 0x000000FFu) != 0u);
        chi += ((wd[i] & 0xFFFFFF00u) != 0u);
    }
    if (clo) atomicAdd(&s_clo, clo);
    if (chi) atomicAdd(&s_chi, chi);
    // zero-fill packed small outputs (d_out is re-poisoned before every call)
    for (int u = tid; u < U; u += 256) {
        out_mask[b * U + u] = 0.0f;
        out_idx[b * U + u]  = 0.0f;
        out_conf[b * U + u] = 0.0f;
    }
    __syncthreads();
    if (tid == 0) s_flag = (s_chi == 0) ? 1 : ((s_clo == 0) ? 2 : 0);
    __syncthreads();
    const int flag = s_flag;
    const int base = b * L_;
    int vals[16];
    int cnt = 0;
#pragma unroll
    for (int j = 0; j < 16; ++j) {
        int v = mask_val(mask, flag, base + tid * 16 + j);
        vals[j] = v;
        cnt += v;
    }
    scan[tid] = cnt;
    __syncthreads();
    for (int off = 1; off < 256; off <<= 1) {
        int v   = scan[tid];
        int add = (tid >= off) ? scan[tid - off] : 0;
        __syncthreads();
        scan[tid] = v + add;
        __syncthreads();
    }
    const int excl = scan[tid] - cnt;
    if (tid == 0) counts[b] = scan[255];
    int u = excl;
#pragma unroll
    for (int j = 0; j < 16; ++j) {
        if (vals[j]) {
            const int t = tid * 16 + j;
            t_idx[b * U + u]    = t;
            out_mask[b * U + u] = 1.0f;
            out_idx[b * U + u]  = (float)t;
            out_conf[b * U + u] = conf_in[base + t];
            ++u;
        }
    }
}

// ----------------------------------------------------------------- wconv ----
__global__ __launch_bounds__(256) void wconv_kernel(
    const float* __restrict__ W, unsigned short* __restrict__ Whi,
    unsigned short* __restrict__ Wlo) {
    const int i = (blockIdx.x * 256 + threadIdx.x) * 4;
    const float4 v = *(const float4*)&W[i];
    ushort4 hi, lo;
    hi.x = bf16_rne(v.x); lo.x = bf16_rne(v.x - bf16_f32(hi.x));
    hi.y = bf16_rne(v.y); lo.y = bf16_rne(v.y - bf16_f32(hi.y));
    hi.z = bf16_rne(v.z); lo.z = bf16_rne(v.z - bf16_f32(hi.z));
    hi.w = bf16_rne(v.w); lo.w = bf16_rne(v.w - bf16_f32(hi.w));
    *(ushort4*)&Whi[i] = hi;
    *(ushort4*)&Wlo[i] = lo;
}

// ------------------------------------------------------------------ pool ----
__global__ __launch_bounds__(256) void pool_kernel(
    const float* __restrict__ emb, const float* __restrict__ cs,
    const int* __restrict__ counts, const int* __restrict__ t_idx,
    unsigned short* __restrict__ Phi, unsigned short* __restrict__ Plo,
    int U) {
    const int m = blockIdx.x;  // b*U + u
    const int b = m / U, u = m - b * U;
    if (u >= counts[b]) return;
    const int t     = t_idx[m];
    const int start = (t - POOLW + 1) > 0 ? (t - POOLW + 1) : 0;
    float wsum = 0.f;
    for (int s = start; s <= t; ++s) wsum += cs[b * L_ + s];
    const float inv = 1.0f / (wsum + EPS_);
    const int d0 = threadIdx.x * 4;
    float4 acc = make_float4(0.f, 0.f, 0.f, 0.f);
    for (int s = start; s <= t; ++s) {
        const float w  = cs[b * L_ + s];
        const float4 e = *(const float4*)&emb[((size_t)(b * L_ + s)) * D_ + d0];
        acc.x += w * e.x; acc.y += w * e.y; acc.z += w * e.z; acc.w += w * e.w;
    }
    acc.x *= inv; acc.y *= inv; acc.z *= inv; acc.w *= inv;
    ushort4 hi, lo;
    hi.x = bf16_rne(acc.x); lo.x = bf16_rne(acc.x - bf16_f32(hi.x));
    hi.y = bf16_rne(acc.y); lo.y = bf16_rne(acc.y - bf16_f32(hi.y));
    hi.z = bf16_rne(acc.z); lo.z = bf16_rne(acc.z - bf16_f32(hi.z));
    hi.w = bf16_rne(acc.w); lo.w = bf16_rne(acc.w - bf16_f32(hi.w));
    *(ushort4*)&Phi[(size_t)m * D_ + d0] = hi;
    *(ushort4*)&Plo[(size_t)m * D_ + d0] = lo;
}

// ------------------------------------------------------------------ gemm ----
// Split-K: block = (mt, kt, nt) computes 64x64 partial over K-chunk 256,
// atomicAdds into C. Block 64x64 / 4 waves 2x2 / wave 32x32 (2x2 frags).
// split-bf16: AhBh + AhBl + AlBh. Fragments loaded directly from global.
__global__ __launch_bounds__(256, 8) void gemm_kernel(
    const unsigned short* __restrict__ Phi, const unsigned short* __restrict__ Plo,
    const unsigned short* __restrict__ Whi, const unsigned short* __restrict__ Wlo,
    const float* __restrict__ bias, const int* __restrict__ counts,
    float* __restrict__ C, int M, int U, int MB) {
    // bijective m204 swizzle -> XCD-contiguous wg ranges; decomposition puts
    // mt outermost so each XCD owns a narrow A-slice (L2-resident).
    const int nwg = MB * KSPLIT * NB_;
    const int q = nwg >> 3, r = nwg & 7;
    const int xcd = blockIdx.x & 7, pos = blockIdx.x >> 3;
    const int wg =
        (xcd < r ? xcd * (q + 1) : r * (q + 1) + (xcd - r) * q) + pos;
    const int mt  = wg / (KSPLIT * NB_);
    const int rem = wg - mt * (KSPLIT * NB_);
    const int kt  = rem >> 4;   // 0..KSPLIT-1
    const int nt  = rem & 15;

    const int tid  = threadIdx.x;
    const int w    = tid >> 6;
    const int lane = tid & 63;
    const int bm = mt * 64, bn = nt * 64, k0 = kt * KCHUNK;
    const int wm = (w >> 1) * 32, wn = (w & 1) * 32;
    const int lr = lane & 15;
    const int lk = (lane >> 4) * 8;

    const size_t aoff0 = (size_t)(bm + wm + lr) * D_ + lk;
    const size_t aoff1 = aoff0 + (size_t)16 * D_;
    const size_t boff0 = (size_t)(bn + wn + lr) * D_ + lk;
    const size_t boff1 = boff0 + (size_t)16 * D_;

    f32x4 acc[2][2] = {};
#pragma unroll
    for (int k = k0; k < k0 + KCHUNK; k += 32) {
        bf16x8 ah0 = *(const bf16x8*)(Phi + aoff0 + k);
        bf16x8 ah1 = *(const bf16x8*)(Phi + aoff1 + k);
        bf16x8 al0 = *(const bf16x8*)(Plo + aoff0 + k);
        bf16x8 al1 = *(const bf16x8*)(Plo + aoff1 + k);
        bf16x8 bh0 = *(const bf16x8*)(Whi + boff0 + k);
        bf16x8 bh1 = *(const bf16x8*)(Whi + boff1 + k);
        bf16x8 bl0 = *(const bf16x8*)(Wlo + boff0 + k);
        bf16x8 bl1 = *(const bf16x8*)(Wlo + boff1 + k);
        __builtin_amdgcn_s_setprio(1);
        acc[0][0] = __builtin_amdgcn_mfma_f32_16x16x32_bf16(ah0, bh0, acc[0][0], 0, 0, 0);
        acc[0][1] = __builtin_amdgcn_mfma_f32_16x16x32_bf16(ah0, bh1, acc[0][1], 0, 0, 0);
        acc[1][0] = __builtin_amdgcn_mfma_f32_16x16x32_bf16(ah1, bh0, acc[1][0], 0, 0, 0);
        acc[1][1] = __builtin_amdgcn_mfma_f32_16x16x32_bf16(ah1, bh1, acc[1][1], 0, 0, 0);
        acc[0][0] = __builtin_amdgcn_mfma_f32_16x16x32_bf16(ah0, bl0, acc[0][0], 0, 0, 0);
        acc[0][1] = __builtin_amdgcn_mfma_f32_16x16x32_bf16(ah0, bl1, acc[0][1], 0, 0, 0);
        acc[1][0] = __builtin_amdgcn_mfma_f32_16x16x32_bf16(ah1, bl0, acc[1][0], 0, 0, 0);
        acc[1][1] = __builtin_amdgcn_mfma_f32_16x16x32_bf16(ah1, bl1, acc[1][1], 0, 0, 0);
        acc[0][0] = __builtin_amdgcn_mfma_f32_16x16x32_bf16(al0, bh0, acc[0][0], 0, 0, 0);
        acc[0][1] = __builtin_amdgcn_mfma_f32_16x16x32_bf16(al0, bh1, acc[0][1], 0, 0, 0);
        acc[1][0] = __builtin_amdgcn_mfma_f32_16x16x32_bf16(al1, bh0, acc[1][0], 0, 0, 0);
        acc[1][1] = __builtin_amdgcn_mfma_f32_16x16x32_bf16(al1, bh1, acc[1][1], 0, 0, 0);
        __builtin_amdgcn_s_setprio(0);
    }
    // epilogue: atomic accumulate; kt==0 adds bias; inactive rows skipped
    // (C pre-zeroed by memset, so inactive slots are exactly 0).
#pragma unroll
    for (int i = 0; i < 2; ++i)
#pragma unroll
        for (int j = 0; j < 2; ++j) {
            const int n  = bn + wn + j * 16 + lr;
            const float bv = (kt == 0) ? bias[n] : 0.0f;
#pragma unroll
            for (int rr = 0; rr < 4; ++rr) {
                const int m = bm + wm + i * 16 + (lane >> 4) * 4 + rr;
                if (m >= M) continue;
                const int b_ = m / U;
                const int u  = m - b_ * U;
                if (u < counts[b_])
                    atomicAdd(&C[(size_t)m * D_ + n], acc[i][j][rr] + bv);
            }
        }
}

// ---------------------------------------------------------------- launch ----
extern "C" void kernel_launch(void* const* d_in, const int* in_sizes, int n_in,
                              void* d_out, int out_size, void* d_ws,
                              size_t ws_size, hipStream_t stream) {
    const float* emb     = (const float*)d_in[0];
    const void*  mask    = d_in[1];
    const float* cs      = (const float*)d_in[2];
    const float* conf_in = (const float*)d_in[3];
    const float* W       = (const float*)d_in[4];
    const float* bias    = (const float*)d_in[5];

    const int U    = out_size / (B_ * (D_ + 3));
    const int M    = B_ * U;
    const int Mpad = (M + 63) & ~63;

    float* out_chunks = (float*)d_out;                  // (B,U,D)
    float* out_mask   = out_chunks + (size_t)M * D_;    // (B,U)
    float* out_idx    = out_mask + M;                   // (B,U)
    float* out_conf   = out_idx + M;                    // (B,U)

    // workspace layout (16B-aligned chunks)
    char* ws = (char*)d_ws;
    int* counts = (int*)ws;                                   // 8 ints
    int* t_idx  = (int*)(ws + 256);                           // Mpad ints
    size_t off  = (256 + (size_t)Mpad * 4 + 255) & ~(size_t)255;
    unsigned short* Phi = (unsigned short*)(ws + off);        // Mpad*D bf16
    off += (size_t)Mpad * D_ * 2;
    unsigned short* Plo = (unsigned short*)(ws + off);
    off += (size_t)Mpad * D_ * 2;
    unsigned short* Whi = (unsigned short*)(ws + off);        // D*D bf16
    off += (size_t)D_ * D_ * 2;
    unsigned short* Wlo = (unsigned short*)(ws + off);

    // chunks must start at 0 (atomic accumulation + inactive-slot zeros)
    hipMemsetAsync(out_chunks, 0, (size_t)M * D_ * sizeof(float), stream);

    pack_kernel<<<B_, 256, 0, stream>>>(mask, conf_in, counts, t_idx,
                                        out_mask, out_idx, out_conf, U);
    wconv_kernel<<<D_ * D_ / 1024, 256, 0, stream>>>(W, Whi, Wlo);
    pool_kernel<<<M, 256, 0, stream>>>(emb, cs, counts, t_idx, Phi, Plo, U);
    const int MB = Mpad / 64;
    gemm_kernel<<<MB * KSPLIT * NB_, 256, 0, stream>>>(
        Phi, Plo, Whi, Wlo, bias, counts, out_chunks, M, U, MB);
}

// Round 5
// 256.017 us; speedup vs baseline: 1.1434x; 1.1092x over previous
//
#include <hip/hip_runtime.h>

// BoundaryChunker — MI355X (gfx950), round 5
// Round-5 change: TILE-PACKED operand layouts. Rounds 2-4 showed dur_us
// invariant (~90us) across occupancy 17->61% => shared-throughput wall, not
// latency: fragment loads at stride 2048B concentrate their 16 lines onto ~2
// L2 channels (8-way channel conflict). Fix: pool/wconv write A/W in MFMA
// fragment order (16-row x 32-k = 1KB contiguous blocks, lane-ordered), so
// every GEMM load is base+lane*16B -> 16 consecutive lines, channel-uniform.
// Split-K=4 + atomicAdd + m-chunked XCD swizzle kept from round 4.

#define B_ 8
#define L_ 4096
#define D_ 1024
#define POOLW 5
#define EPS_ 1e-6f
#define KSPLIT 4
#define KCHUNK (D_ / KSPLIT)   // 256
#define NB_ 16                 // D_/64 n-tiles

typedef __attribute__((ext_vector_type(8))) short bf16x8;
typedef __attribute__((ext_vector_type(4))) float f32x4;

__device__ __forceinline__ unsigned short bf16_rne(float v) {
    unsigned u = __float_as_uint(v);
    unsigned r = u + 0x7FFFu + ((u >> 16) & 1u);
    return (unsigned short)(r >> 16);
}
__device__ __forceinline__ float bf16_f32(unsigned short h) {
    return __uint_as_float(((unsigned)h) << 16);
}

// packed element offset for matrix row m (or n), column k:
// tile16 = m>>4 owns a contiguous [16*D_] block; within, k-step ks=k>>5 owns
// 512 elems; lane-slot l = (m&15) + 16*((k>>3)&3); elem = l*8 + (k&7).
__device__ __forceinline__ size_t packed_off(int m, int k) {
    return (size_t)(m >> 4) * (16 * D_) + (size_t)(k >> 5) * 512 +
           (size_t)(((m & 15) + 16 * ((k >> 3) & 3)) * 8 + (k & 7));
}

__device__ __forceinline__ int mask_val(const void* mask, int flag, int i) {
    if (flag == 0) return ((const unsigned char*)mask)[i] != 0;
    if (flag == 1) return ((const int*)mask)[i] != 0;
    return ((const float*)mask)[i] != 0.0f;
}

// ------------------------------------------------------------------ pack ----
__global__ __launch_bounds__(256) void pack_kernel(
    const void* __restrict__ mask, const float* __restrict__ conf_in,
    int* __restrict__ counts, int* __restrict__ t_idx,
    float* __restrict__ out_mask, float* __restrict__ out_idx,
    float* __restrict__ out_conf, int U) {
    const int b   = blockIdx.x;
    const int tid = threadIdx.x;
    __shared__ int s_clo, s_chi, s_flag;
    __shared__ int scan[256];
    if (tid == 0) { s_clo = 0; s_chi = 0; }
    __syncthreads();
    // dtype detect on this block's 4KB slice of raw bytes:
    // i32(1) -> only byte%4==0 nonzero; f32(1.0f) -> only high bytes; u8 -> both.
    const uint4 wv = ((const uint4*)mask)[b * 256 + tid];
    const unsigned wd[4] = {wv.x, wv.y, wv.z, wv.w};
    int clo = 0, chi = 0;
#pragma unroll
    for (int i = 0; i < 4; ++i) {
        clo += ((wd[i] & 0x000000FFu) != 0u);
        chi += ((wd[i] & 0xFFFFFF00u) != 0u);
    }
    if (clo) atomicAdd(&s_clo, clo);
    if (chi) atomicAdd(&s_chi, chi);
    // zero-fill packed small outputs (d_out is re-poisoned before every call)
    for (int u = tid; u < U; u += 256) {
        out_mask[b * U + u] = 0.0f;
        out_idx[b * U + u]  = 0.0f;
        out_conf[b * U + u] = 0.0f;
    }
    __syncthreads();
    if (tid == 0) s_flag = (s_chi == 0) ? 1 : ((s_clo == 0) ? 2 : 0);
    __syncthreads();
    const int flag = s_flag;
    const int base = b * L_;
    int vals[16];
    int cnt = 0;
#pragma unroll
    for (int j = 0; j < 16; ++j) {
        int v = mask_val(mask, flag, base + tid * 16 + j);
        vals[j] = v;
        cnt += v;
    }
    scan[tid] = cnt;
    __syncthreads();
    for (int off = 1; off < 256; off <<= 1) {
        int v   = scan[tid];
        int add = (tid >= off) ? scan[tid - off] : 0;
        __syncthreads();
        scan[tid] = v + add;
        __syncthreads();
    }
    const int excl = scan[tid] - cnt;
    if (tid == 0) counts[b] = scan[255];
    int u = excl;
#pragma unroll
    for (int j = 0; j < 16; ++j) {
        if (vals[j]) {
            const int t = tid * 16 + j;
            t_idx[b * U + u]    = t;
            out_mask[b * U + u] = 1.0f;
            out_idx[b * U + u]  = (float)t;
            out_conf[b * U + u] = conf_in[base + t];
            ++u;
        }
    }
}

// ----------------------------------------------------------------- wconv ----
// W f32 [n][k] -> packed-tile bf16 hi/lo. Thread handles 4 consecutive k of
// one n-row; those 4 elems are contiguous within one packed lane-slot.
__global__ __launch_bounds__(256) void wconv_kernel(
    const float* __restrict__ W, unsigned short* __restrict__ Whi,
    unsigned short* __restrict__ Wlo) {
    const int i = (blockIdx.x * 256 + threadIdx.x) * 4;
    const int n = i >> 10, k = i & 1023;
    const float4 v = *(const float4*)&W[i];
    ushort4 hi, lo;
    hi.x = bf16_rne(v.x); lo.x = bf16_rne(v.x - bf16_f32(hi.x));
    hi.y = bf16_rne(v.y); lo.y = bf16_rne(v.y - bf16_f32(hi.y));
    hi.z = bf16_rne(v.z); lo.z = bf16_rne(v.z - bf16_f32(hi.z));
    hi.w = bf16_rne(v.w); lo.w = bf16_rne(v.w - bf16_f32(hi.w));
    const size_t o = packed_off(n, k);
    *(ushort4*)&Whi[o] = hi;
    *(ushort4*)&Wlo[o] = lo;
}

// ------------------------------------------------------------------ pool ----
// One block per (b,u) slot; writes pooled vector into packed-tile hi/lo.
__global__ __launch_bounds__(256) void pool_kernel(
    const float* __restrict__ emb, const float* __restrict__ cs,
    const int* __restrict__ counts, const int* __restrict__ t_idx,
    unsigned short* __restrict__ Phi, unsigned short* __restrict__ Plo,
    int U) {
    const int m = blockIdx.x;  // b*U + u
    const int b = m / U, u = m - b * U;
    if (u >= counts[b]) return;
    const int t     = t_idx[m];
    const int start = (t - POOLW + 1) > 0 ? (t - POOLW + 1) : 0;
    float wsum = 0.f;
    for (int s = start; s <= t; ++s) wsum += cs[b * L_ + s];
    const float inv = 1.0f / (wsum + EPS_);
    const int d0 = threadIdx.x * 4;
    float4 acc = make_float4(0.f, 0.f, 0.f, 0.f);
    for (int s = start; s <= t; ++s) {
        const float w  = cs[b * L_ + s];
        const float4 e = *(const float4*)&emb[((size_t)(b * L_ + s)) * D_ + d0];
        acc.x += w * e.x; acc.y += w * e.y; acc.z += w * e.z; acc.w += w * e.w;
    }
    acc.x *= inv; acc.y *= inv; acc.z *= inv; acc.w *= inv;
    ushort4 hi, lo;
    hi.x = bf16_rne(acc.x); lo.x = bf16_rne(acc.x - bf16_f32(hi.x));
    hi.y = bf16_rne(acc.y); lo.y = bf16_rne(acc.y - bf16_f32(hi.y));
    hi.z = bf16_rne(acc.z); lo.z = bf16_rne(acc.z - bf16_f32(hi.z));
    hi.w = bf16_rne(acc.w); lo.w = bf16_rne(acc.w - bf16_f32(hi.w));
    const size_t o = packed_off(m, d0);
    *(ushort4*)&Phi[o] = hi;
    *(ushort4*)&Plo[o] = lo;
}

// ------------------------------------------------------------------ gemm ----
// Split-K block = (mt,kt,nt), 64x64 partial over K-chunk 256, atomicAdd to C.
// Packed operands: fragment load = base + lane*16B (fully coalesced 1KB).
__global__ __launch_bounds__(256) void gemm_kernel(
    const unsigned short* __restrict__ Phi, const unsigned short* __restrict__ Plo,
    const unsigned short* __restrict__ Whi, const unsigned short* __restrict__ Wlo,
    const float* __restrict__ bias, const int* __restrict__ counts,
    float* __restrict__ C, int M, int U, int MB) {
    const int nwg = MB * KSPLIT * NB_;
    const int q = nwg >> 3, r = nwg & 7;
    const int xcd = blockIdx.x & 7, pos = blockIdx.x >> 3;
    const int wg =
        (xcd < r ? xcd * (q + 1) : r * (q + 1) + (xcd - r) * q) + pos;
    const int mt  = wg / (KSPLIT * NB_);
    const int rem = wg - mt * (KSPLIT * NB_);
    const int kt  = rem >> 4;   // 0..KSPLIT-1
    const int nt  = rem & 15;

    const int tid  = threadIdx.x;
    const int w    = tid >> 6;
    const int lane = tid & 63;
    const int bm = mt * 64, bn = nt * 64, k0 = kt * KCHUNK;
    const int wm = (w >> 1) * 32, wn = (w & 1) * 32;

    // packed fragment bases: tile16 index * 16*D_ + ks*512 + lane*8
    const int amt = (bm + wm) >> 4;
    const int bnt = (bn + wn) >> 4;
    size_t aoff0 = (size_t)amt * (16 * D_) + (size_t)(k0 >> 5) * 512 + lane * 8;
    size_t aoff1 = aoff0 + (size_t)(16 * D_);
    size_t boff0 = (size_t)bnt * (16 * D_) + (size_t)(k0 >> 5) * 512 + lane * 8;
    size_t boff1 = boff0 + (size_t)(16 * D_);

    f32x4 acc[2][2] = {};
#pragma unroll
    for (int ks = 0; ks < KCHUNK / 32; ++ks) {
        const size_t sa = (size_t)ks * 512;
        bf16x8 ah0 = *(const bf16x8*)(Phi + aoff0 + sa);
        bf16x8 ah1 = *(const bf16x8*)(Phi + aoff1 + sa);
        bf16x8 al0 = *(const bf16x8*)(Plo + aoff0 + sa);
        bf16x8 al1 = *(const bf16x8*)(Plo + aoff1 + sa);
        bf16x8 bh0 = *(const bf16x8*)(Whi + boff0 + sa);
        bf16x8 bh1 = *(const bf16x8*)(Whi + boff1 + sa);
        bf16x8 bl0 = *(const bf16x8*)(Wlo + boff0 + sa);
        bf16x8 bl1 = *(const bf16x8*)(Wlo + boff1 + sa);
        __builtin_amdgcn_s_setprio(1);
        acc[0][0] = __builtin_amdgcn_mfma_f32_16x16x32_bf16(ah0, bh0, acc[0][0], 0, 0, 0);
        acc[0][1] = __builtin_amdgcn_mfma_f32_16x16x32_bf16(ah0, bh1, acc[0][1], 0, 0, 0);
        acc[1][0] = __builtin_amdgcn_mfma_f32_16x16x32_bf16(ah1, bh0, acc[1][0], 0, 0, 0);
        acc[1][1] = __builtin_amdgcn_mfma_f32_16x16x32_bf16(ah1, bh1, acc[1][1], 0, 0, 0);
        acc[0][0] = __builtin_amdgcn_mfma_f32_16x16x32_bf16(ah0, bl0, acc[0][0], 0, 0, 0);
        acc[0][1] = __builtin_amdgcn_mfma_f32_16x16x32_bf16(ah0, bl1, acc[0][1], 0, 0, 0);
        acc[1][0] = __builtin_amdgcn_mfma_f32_16x16x32_bf16(ah1, bl0, acc[1][0], 0, 0, 0);
        acc[1][1] = __builtin_amdgcn_mfma_f32_16x16x32_bf16(ah1, bl1, acc[1][1], 0, 0, 0);
        acc[0][0] = __builtin_amdgcn_mfma_f32_16x16x32_bf16(al0, bh0, acc[0][0], 0, 0, 0);
        acc[0][1] = __builtin_amdgcn_mfma_f32_16x16x32_bf16(al0, bh1, acc[0][1], 0, 0, 0);
        acc[1][0] = __builtin_amdgcn_mfma_f32_16x16x32_bf16(al1, bh0, acc[1][0], 0, 0, 0);
        acc[1][1] = __builtin_amdgcn_mfma_f32_16x16x32_bf16(al1, bh1, acc[1][1], 0, 0, 0);
        __builtin_amdgcn_s_setprio(0);
    }
    // epilogue: atomic accumulate; kt==0 adds bias; inactive rows skipped
    // (C pre-zeroed by memset, so inactive slots are exactly 0).
    const int lr = lane & 15;
#pragma unroll
    for (int i = 0; i < 2; ++i)
#pragma unroll
        for (int j = 0; j < 2; ++j) {
            const int n  = bn + wn + j * 16 + lr;
            const float bv = (kt == 0) ? bias[n] : 0.0f;
#pragma unroll
            for (int rr = 0; rr < 4; ++rr) {
                const int m = bm + wm + i * 16 + (lane >> 4) * 4 + rr;
                if (m >= M) continue;
                const int b_ = m / U;
                const int u  = m - b_ * U;
                if (u < counts[b_])
                    atomicAdd(&C[(size_t)m * D_ + n], acc[i][j][rr] + bv);
            }
        }
}

// ---------------------------------------------------------------- launch ----
extern "C" void kernel_launch(void* const* d_in, const int* in_sizes, int n_in,
                              void* d_out, int out_size, void* d_ws,
                              size_t ws_size, hipStream_t stream) {
    const float* emb     = (const float*)d_in[0];
    const void*  mask    = d_in[1];
    const float* cs      = (const float*)d_in[2];
    const float* conf_in = (const float*)d_in[3];
    const float* W       = (const float*)d_in[4];
    const float* bias    = (const float*)d_in[5];

    const int U    = out_size / (B_ * (D_ + 3));
    const int M    = B_ * U;
    const int Mpad = (M + 63) & ~63;

    float* out_chunks = (float*)d_out;                  // (B,U,D)
    float* out_mask   = out_chunks + (size_t)M * D_;    // (B,U)
    float* out_idx    = out_mask + M;                   // (B,U)
    float* out_conf   = out_idx + M;                    // (B,U)

    // workspace layout (16B-aligned chunks)
    char* ws = (char*)d_ws;
    int* counts = (int*)ws;                                   // 8 ints
    int* t_idx  = (int*)(ws + 256);                           // Mpad ints
    size_t off  = (256 + (size_t)Mpad * 4 + 255) & ~(size_t)255;
    unsigned short* Phi = (unsigned short*)(ws + off);        // Mpad*D bf16 (packed tiles)
    off += (size_t)Mpad * D_ * 2;
    unsigned short* Plo = (unsigned short*)(ws + off);
    off += (size_t)Mpad * D_ * 2;
    unsigned short* Whi = (unsigned short*)(ws + off);        // D*D bf16 (packed tiles)
    off += (size_t)D_ * D_ * 2;
    unsigned short* Wlo = (unsigned short*)(ws + off);

    // chunks must start at 0 (atomic accumulation + inactive-slot zeros)
    hipMemsetAsync(out_chunks, 0, (size_t)M * D_ * sizeof(float), stream);

    pack_kernel<<<B_, 256, 0, stream>>>(mask, conf_in, counts, t_idx,
                                        out_mask, out_idx, out_conf, U);
    wconv_kernel<<<D_ * D_ / 1024, 256, 0, stream>>>(W, Whi, Wlo);
    pool_kernel<<<M, 256, 0, stream>>>(emb, cs, counts, t_idx, Phi, Plo, U);
    const int MB = Mpad / 64;
    gemm_kernel<<<MB * KSPLIT * NB_, 256, 0, stream>>>(
        Phi, Plo, Whi, Wlo, bias, counts, out_chunks, M, U, MB);
}